// Round 14
// baseline (230.520 us; speedup 1.0000x reference)
//
#include <hip/hip_runtime.h>
#include <hip/hip_bf16.h>
#include <math.h>

#define SDIM 42
#define CDIM 96
#define NTOK 74088          // 42^3
#define NWIN 216
#define NSEQ 343            // 7^3
#define NTOT 7112448        // NWIN*3*NSEQ*32 == NTOK*96
#define QK_SCALE 0.17677669529663687f
#define LN_EPS 1e-5f

typedef short short8 __attribute__((ext_vector_type(8)));
typedef float f32x4 __attribute__((ext_vector_type(4)));
typedef unsigned eu4 __attribute__((ext_vector_type(4)));
union I4S8 { int4 i; short8 s; };

__device__ __forceinline__ int tok_index(int w, int n) {
    int wq = w / 36;
    int wrem = w - wq * 36;
    int wh = wrem / 6;
    int ww = wrem - wh * 6;
    int ps = n / 49;
    int prem = n - ps * 49;
    int ph = prem / 7;
    int pw = prem - ph * 7;
    int s = wq * 7 + ps + 3; if (s >= SDIM) s -= SDIM;
    int h = wh * 7 + ph + 3; if (h >= SDIM) h -= SDIM;
    int c = ww * 7 + pw + 3; if (c >= SDIM) c -= SDIM;
    return (s * SDIM + h) * SDIM + c;
}

__device__ __forceinline__ unsigned pk2(float a, float b) {
    unsigned ua = (unsigned)__bfloat16_as_ushort(__float2bfloat16(a));
    unsigned ub = (unsigned)__bfloat16_as_ushort(__float2bfloat16(b));
    return ua | (ub << 16);
}

// Branch-free erf (Abramowitz-Stegun 7.1.26, |err| < 1.5e-7)
__device__ __forceinline__ float fast_erf(float x) {
    float ax = fabsf(x);
    float t = 1.0f / (1.0f + 0.3275911f * ax);
    float y = t*(0.254829592f + t*(-0.284496736f +
              t*(1.421413741f + t*(-1.453152027f + t*1.061405429f))));
    float r = 1.0f - y * __expf(-ax*ax);
    return copysignf(r, x);
}
__device__ __forceinline__ float gelu(float v) {
    return 0.5f * v * (1.0f + fast_erf(v * 0.70710678118654752f));
}

// ------------- Kernel 0b: transpose+cast all GEMM weights to bf16 -----------
__global__ __launch_bounds__(384) void k_wcast(
    const float* __restrict__ w1, const float* __restrict__ w2,
    const float* __restrict__ pw, const float* __restrict__ qkvw,
    __hip_bfloat16* __restrict__ w1t, __hip_bfloat16* __restrict__ w2t,
    __hip_bfloat16* __restrict__ pwt, __hip_bfloat16* __restrict__ qkvt)
{
    int b = blockIdx.x, t = threadIdx.x;
    if (b < 384) {
        if (t < 96) w1t[(size_t)b*96 + t] = __float2bfloat16(w1[(size_t)t*384 + b]);
    } else if (b < 480) {
        int r = b - 384;
        w2t[(size_t)r*384 + t] = __float2bfloat16(w2[(size_t)t*96 + r]);
    } else if (b < 576) {
        int r = b - 480;
        if (t < 96) pwt[(size_t)r*96 + t] = __float2bfloat16(pw[(size_t)t*96 + r]);
    } else {
        int c = b - 576;
        if (t < 96) qkvt[(size_t)c*96 + t] = __float2bfloat16(qkvw[(size_t)t*288 + c]);
    }
}

// --- Kernel 1 (fused): LN1+gather+QKV GEMM | mask scan | bias table ---------
__global__ __launch_bounds__(256) void k_fused_prep(
    const float* __restrict__ x,
    const float* __restrict__ n1w, const float* __restrict__ n1b,
    const __hip_bfloat16* __restrict__ qkvt, const float* __restrict__ qkvb,
    __hip_bfloat16* __restrict__ qb, __hip_bfloat16* __restrict__ kb,
    __hip_bfloat16* __restrict__ vb,
    const float* __restrict__ mask, unsigned* __restrict__ mflag,
    const float* __restrict__ rpb, float* __restrict__ bg)
{
    __shared__ __align__(16) __hip_bfloat16 sX[64*104];
    __shared__ unsigned sFlag;
    const int b = blockIdx.x;
    const int tid = threadIdx.x;

    if (b >= 1296 + NWIN) {
        // ---- bias table ----
        const int p = b - (1296 + NWIN);
        const int m = p % NSEQ, hh = p / NSEQ;
        const int a0 = m / 49, ar = m - a0*49, a1 = ar / 7, a2 = ar - a1*7;
        for (int n = tid; n < NSEQ; n += 256) {
            int b0 = n / 49, br = n - b0*49, b1 = br / 7, b2 = br - b1*7;
            int idx = (a0 - b0 + 6)*20 + (a1 - b1 + 6)*13 + (a2 - b2 + 6);
            bg[((size_t)hh*NSEQ + m)*NSEQ + n] = rpb[idx*3 + hh];
        }
        return;
    }
    if (b >= 1296) {
        // ---- mask scan (NT loads: 101MB read-once stream) ----
        const int w = b - 1296;
        if (tid == 0) sFlag = 0;
        __syncthreads();
        const unsigned* p = (const unsigned*)(mask + (size_t)w * NSEQ * NSEQ);
        unsigned acc = 0;
        const eu4* p4 = (const eu4*)p;
        for (int i = tid; i < (NSEQ*NSEQ)/4; i += 256) {
            eu4 v = __builtin_nontemporal_load(p4 + i);
            acc |= (v[0] << 1) | (v[1] << 1) | (v[2] << 1) | (v[3] << 1);
        }
        if (tid == 0) acc |= (p[NSEQ*NSEQ - 1] << 1);
        if (__any(acc != 0) && (tid & 63) == 0) atomicOr(&sFlag, 1u);
        __syncthreads();
        if (tid == 0) mflag[w] = sFlag;
        return;
    }

    // ---- LN1 + gather + QKV GEMM ----
    const int w  = b / 6;
    const int n0 = (b - w*6) * 64;
    const int g = tid >> 5, l = tid & 31;
    {
        const float lw0 = n1w[l], lw1 = n1w[l+32], lw2 = n1w[l+64];
        const float lb0 = n1b[l], lb1 = n1b[l+32], lb2 = n1b[l+64];
        for (int rr = 0; rr < 8; ++rr) {
            int row = g * 8 + rr;
            int n = n0 + row;
            if (n < NSEQ) {
                const float* xr = x + (size_t)tok_index(w, n) * CDIM;
                float x0 = __builtin_nontemporal_load(xr + l);
                float x1 = __builtin_nontemporal_load(xr + l + 32);
                float x2 = __builtin_nontemporal_load(xr + l + 64);
                float s = x0 + x1 + x2;
                #pragma unroll
                for (int m = 16; m; m >>= 1) s += __shfl_xor(s, m, 32);
                float mu = s * (1.0f/96.0f);
                float d0 = x0-mu, d1 = x1-mu, d2 = x2-mu;
                float vv = d0*d0 + d1*d1 + d2*d2;
                #pragma unroll
                for (int m = 16; m; m >>= 1) vv += __shfl_xor(vv, m, 32);
                float rstd = rsqrtf(vv * (1.0f/96.0f) + LN_EPS);
                sX[row*104 + l]    = __float2bfloat16(d0 * rstd * lw0 + lb0);
                sX[row*104 + l+32] = __float2bfloat16(d1 * rstd * lw1 + lb1);
                sX[row*104 + l+64] = __float2bfloat16(d2 * rstd * lw2 + lb2);
            } else {
                sX[row*104 + l]    = __float2bfloat16(0.f);
                sX[row*104 + l+32] = __float2bfloat16(0.f);
                sX[row*104 + l+64] = __float2bfloat16(0.f);
            }
        }
    }
    __syncthreads();

    const int wv = tid >> 6, lane = tid & 63;
    const int l15 = lane & 15, h = lane >> 4;
    const int trow = wv*16 + l15;
    const int n = n0 + trow;

    I4S8 bx[3];
    #pragma unroll
    for (int ks = 0; ks < 3; ++ks)
        bx[ks].i = *(const int4*)&sX[trow*104 + ks*32 + h*8];

    for (int nt = 0; nt < 18; ++nt) {
        f32x4 acc = {0.f,0.f,0.f,0.f};
        #pragma unroll
        for (int ks = 0; ks < 3; ++ks) {
            I4S8 af;
            af.i = *(const int4*)(qkvt + (size_t)(nt*16 + l15)*96 + ks*32 + h*8);
            acc = __builtin_amdgcn_mfma_f32_16x16x32_bf16(af.s, bx[ks].s, acc, 0, 0, 0);
        }
        if (n < NSEQ) {
            const int colbase = nt*16 + 4*h;          // [0,288)
            const int sel = colbase / 96;
            const int rem = colbase - sel*96;
            const int head = rem >> 5, d0 = rem & 31;
            float4 bb = *(const float4*)&qkvb[colbase];
            float v0 = acc[0] + bb.x, v1 = acc[1] + bb.y;
            float v2 = acc[2] + bb.z, v3 = acc[3] + bb.w;
            if (sel == 0) { v0 *= QK_SCALE; v1 *= QK_SCALE; v2 *= QK_SCALE; v3 *= QK_SCALE; }
            __hip_bfloat16* dst = (sel == 0 ? qb : (sel == 1 ? kb : vb));
            *(uint2*)&dst[(((size_t)w*3 + head)*NSEQ + n)*32 + d0] =
                make_uint2(pk2(v0, v1), pk2(v2, v3));
        }
    }
}

// ------- Kernel 2: windowed attention via MFMA (streaming, no-max) ----------
template<bool UM>
__device__ __forceinline__ void attn_qloop(
    const __hip_bfloat16* __restrict__ qb, const float* __restrict__ bg,
    const float* __restrict__ mask, __hip_bfloat16* __restrict__ aob,
    const __hip_bfloat16* sK, const __hip_bfloat16* sVT,
    size_t base, int w, int head, int wid, int l15, int h)
{
    for (int mt = wid; mt < 22; mt += 8) {
        const int m = mt*16 + l15;
        const int mc = (m < NSEQ) ? m : (NSEQ-1);

        I4S8 qf;
        qf.i = *(const int4*)(qb + base + (size_t)mc*32 + h*8);

        const float* mrow = mask + ((size_t)w*NSEQ + mc)*NSEQ;
        const float* brow = bg   + ((size_t)head*NSEQ + mc)*NSEQ;

        float lsum = 0.f;
        f32x4 acc0 = {0.f,0.f,0.f,0.f}, acc1 = {0.f,0.f,0.f,0.f};

        auto step = [&](int t, float4 mkA, float4 bsA, float4 mkB, float4 bsB) {
            float p[8];
            {
                I4S8 kf;
                kf.i = *(const int4*)&sK[(t*16 + l15)*32 + h*8];
                f32x4 st = __builtin_amdgcn_mfma_f32_16x16x32_bf16(
                    kf.s, qf.s, (f32x4){0.f,0.f,0.f,0.f}, 0, 0, 0);
                if constexpr (UM) {
                    p[0] = __expf(st[0] + mkA.x + bsA.x);
                    p[1] = __expf(st[1] + mkA.y + bsA.y);
                    p[2] = __expf(st[2] + mkA.z + bsA.z);
                    p[3] = __expf(st[3] + mkA.w + bsA.w);
                } else {
                    p[0] = __expf(st[0] + bsA.x);
                    p[1] = __expf(st[1] + bsA.y);
                    p[2] = __expf(st[2] + bsA.z);
                    p[3] = __expf(st[3] + bsA.w);
                }
                lsum += (p[0] + p[1]) + (p[2] + p[3]);
            }
            {
                I4S8 kf;
                kf.i = *(const int4*)&sK[((t+1)*16 + l15)*32 + h*8];
                f32x4 st = __builtin_amdgcn_mfma_f32_16x16x32_bf16(
                    kf.s, qf.s, (f32x4){0.f,0.f,0.f,0.f}, 0, 0, 0);
                if constexpr (UM) {
                    p[4] = __expf(st[0] + mkB.x + bsB.x);
                    p[5] = __expf(st[1] + mkB.y + bsB.y);
                    p[6] = __expf(st[2] + mkB.z + bsB.z);
                    p[7] = __expf(st[3] + mkB.w + bsB.w);
                } else {
                    p[4] = __expf(st[0] + bsB.x);
                    p[5] = __expf(st[1] + bsB.y);
                    p[6] = __expf(st[2] + bsB.z);
                    p[7] = __expf(st[3] + bsB.w);
                }
                lsum += (p[4] + p[5]) + (p[6] + p[7]);
            }
            I4S8 pf;
            pf.i = make_int4(pk2(p[0], p[1]), pk2(p[2], p[3]),
                             pk2(p[4], p[5]), pk2(p[6], p[7]));
            const int vcol = t*16 + 4*h;
            uint2 va0 = *(const uint2*)&sVT[(l15     )*372 + vcol];
            uint2 vb0 = *(const uint2*)&sVT[(l15     )*372 + vcol + 16];
            uint2 va1 = *(const uint2*)&sVT[(16 + l15)*372 + vcol];
            uint2 vb1 = *(const uint2*)&sVT[(16 + l15)*372 + vcol + 16];
            I4S8 vf0; vf0.i = make_int4(va0.x, va0.y, vb0.x, vb0.y);
            I4S8 vf1; vf1.i = make_int4(va1.x, va1.y, vb1.x, vb1.y);
            acc0 = __builtin_amdgcn_mfma_f32_16x16x32_bf16(vf0.s, pf.s, acc0, 0, 0, 0);
            acc1 = __builtin_amdgcn_mfma_f32_16x16x32_bf16(vf1.s, pf.s, acc1, 0, 0, 0);
        };

        const float4 z4 = {0.f,0.f,0.f,0.f};
        float4 mkA = UM ? *(const float4*)&mrow[4*h]      : z4;
        float4 bsA =      *(const float4*)&brow[4*h];
        float4 mkB = UM ? *(const float4*)&mrow[16 + 4*h] : z4;
        float4 bsB =      *(const float4*)&brow[16 + 4*h];

        #pragma unroll 1
        for (int c = 0; c < 9; ++c) {
            const int nb = (2*c + 2)*16 + 4*h;
            float4 nmkA = UM ? *(const float4*)&mrow[nb]      : z4;
            float4 nbsA =      *(const float4*)&brow[nb];
            float4 nmkB = UM ? *(const float4*)&mrow[nb + 16] : z4;
            float4 nbsB =      *(const float4*)&brow[nb + 16];
            step(2*c, mkA, bsA, mkB, bsB);
            mkA = nmkA; bsA = nbsA; mkB = nmkB; bsB = nbsB;
        }

        {
            float4 nmkA = UM ? *(const float4*)&mrow[320 + 4*h] : z4;
            float4 nbsA =      *(const float4*)&brow[320 + 4*h];
            float4 nmkB = z4, nbsB;
            {
                const int nb = 336 + 4*h;
                int i0 = nb,   c0 = (i0 < NSEQ) ? i0 : (NSEQ-1);
                int i1 = nb+1, c1 = (i1 < NSEQ) ? i1 : (NSEQ-1);
                int i2 = nb+2, c2 = (i2 < NSEQ) ? i2 : (NSEQ-1);
                int i3 = nb+3, c3 = (i3 < NSEQ) ? i3 : (NSEQ-1);
                if constexpr (UM) {
                    nmkB.x = mrow[c0]; nmkB.y = mrow[c1];
                    nmkB.z = mrow[c2]; nmkB.w = mrow[c3];
                }
                nbsB.x = brow[c0]; nbsB.y = brow[c1];
                nbsB.z = brow[c2]; nbsB.w = brow[c3];
            }
            step(18, mkA, bsA, mkB, bsB);
            mkA = nmkA; bsA = nbsA; mkB = nmkB; bsB = nbsB;
        }

        {
            float p[8];
            {
                I4S8 kf;
                kf.i = *(const int4*)&sK[(20*16 + l15)*32 + h*8];
                f32x4 st = __builtin_amdgcn_mfma_f32_16x16x32_bf16(
                    kf.s, qf.s, (f32x4){0.f,0.f,0.f,0.f}, 0, 0, 0);
                if constexpr (UM) {
                    p[0] = __expf(st[0] + mkA.x + bsA.x);
                    p[1] = __expf(st[1] + mkA.y + bsA.y);
                    p[2] = __expf(st[2] + mkA.z + bsA.z);
                    p[3] = __expf(st[3] + mkA.w + bsA.w);
                } else {
                    p[0] = __expf(st[0] + bsA.x);
                    p[1] = __expf(st[1] + bsA.y);
                    p[2] = __expf(st[2] + bsA.z);
                    p[3] = __expf(st[3] + bsA.w);
                }
                lsum += (p[0] + p[1]) + (p[2] + p[3]);
            }
            {
                I4S8 kf;
                kf.i = *(const int4*)&sK[(21*16 + l15)*32 + h*8];
                f32x4 st = __builtin_amdgcn_mfma_f32_16x16x32_bf16(
                    kf.s, qf.s, (f32x4){0.f,0.f,0.f,0.f}, 0, 0, 0);
                float sb[4];
                if constexpr (UM) {
                    sb[0] = mkB.x + bsB.x; sb[1] = mkB.y + bsB.y;
                    sb[2] = mkB.z + bsB.z; sb[3] = mkB.w + bsB.w;
                } else {
                    sb[0] = bsB.x; sb[1] = bsB.y; sb[2] = bsB.z; sb[3] = bsB.w;
                }
                const int nb = 336 + 4*h;
                #pragma unroll
                for (int r = 0; r < 4; ++r) {
                    const int nn = nb + r;
                    float e = 0.f;
                    if (nn < NSEQ) e = __expf(st[r] + sb[r]);
                    p[4+r] = e; lsum += e;
                }
            }
            I4S8 pf;
            pf.i = make_int4(pk2(p[0], p[1]), pk2(p[2], p[3]),
                             pk2(p[4], p[5]), pk2(p[6], p[7]));
            const int vcol = 320 + 4*h;                // cols 343.. are zeroed
            uint2 va0 = *(const uint2*)&sVT[(l15     )*372 + vcol];
            uint2 vb0 = *(const uint2*)&sVT[(l15     )*372 + vcol + 16];
            uint2 va1 = *(const uint2*)&sVT[(16 + l15)*372 + vcol];
            uint2 vb1 = *(const uint2*)&sVT[(16 + l15)*372 + vcol + 16];
            I4S8 vf0; vf0.i = make_int4(va0.x, va0.y, vb0.x, vb0.y);
            I4S8 vf1; vf1.i = make_int4(va1.x, va1.y, vb1.x, vb1.y);
            acc0 = __builtin_amdgcn_mfma_f32_16x16x32_bf16(vf0.s, pf.s, acc0, 0, 0, 0);
            acc1 = __builtin_amdgcn_mfma_f32_16x16x32_bf16(vf1.s, pf.s, acc1, 0, 0, 0);
        }

        lsum += __shfl_xor(lsum, 16, 64);
        lsum += __shfl_xor(lsum, 32, 64);
        const float inv = 1.0f / lsum;

        if (m < NSEQ) {
            __hip_bfloat16* orow = &aob[((size_t)w*NSEQ + m)*CDIM + head*32];
            *(uint2*)&orow[4*h] =
                make_uint2(pk2(acc0[0]*inv, acc0[1]*inv), pk2(acc0[2]*inv, acc0[3]*inv));
            *(uint2*)&orow[16 + 4*h] =
                make_uint2(pk2(acc1[0]*inv, acc1[1]*inv), pk2(acc1[2]*inv, acc1[3]*inv));
        }
    }
}

__global__ __launch_bounds__(512) void k_attn(
    const __hip_bfloat16* __restrict__ qb, const __hip_bfloat16* __restrict__ kb,
    const __hip_bfloat16* __restrict__ vb, const float* __restrict__ bg,
    const float* __restrict__ mask, const unsigned* __restrict__ mflag,
    __hip_bfloat16* __restrict__ aob)
{
    __shared__ __hip_bfloat16 sK[352*32];      // K rows [343][32], 64B stride
    __shared__ __hip_bfloat16 sVT[32*372];     // V^T [32][343], stride 372
    const int tid = threadIdx.x;
    const int v = blockIdx.x;
    const int xcd = v & 7, tt = v >> 3;
    const int j = tt / 3, head = tt - 3*j;
    const int w = xcd + 8*j;
    const size_t base = ((size_t)w*3 + head) * (NSEQ*32);

    {
        const int4* ksrc = (const int4*)(kb + base);
        for (int i = tid; i < NSEQ*4; i += 512) {
            int row = i >> 2, q = i & 3;
            *(int4*)&sK[row*32 + q*8] = ksrc[i];
        }
        const int4* vsrc = (const int4*)(vb + base);
        for (int i = tid; i < NSEQ*4; i += 512) {
            int n = i >> 2, dc = i & 3;
            int4 t = vsrc[i];
            const __hip_bfloat16* tp = (const __hip_bfloat16*)&t;
            #pragma unroll
            for (int k2 = 0; k2 < 8; ++k2) sVT[(dc*8 + k2)*372 + n] = tp[k2];
        }
        for (int i = tid; i < 32*29; i += 512) {   // zero cols 343..371
            int d = i / 29, n = NSEQ + (i - d*29);
            sVT[d*372 + n] = __float2bfloat16(0.f);
        }
    }
    __syncthreads();

    const int wid = tid >> 6, lane = tid & 63;
    const int l15 = lane & 15, h = lane >> 4;

    if (mflag[w] == 0)
        attn_qloop<false>(qb, bg, mask, aob, sK, sVT, base, w, head, wid, l15, h);
    else
        attn_qloop<true>(qb, bg, mask, aob, sK, sVT, base, w, head, wid, l15, h);
}

// ---- Kernel 3: fused proj+residual+LN2+FC1+GELU+FC2+residual ---------------
// Weights LDS-staged (T14 issue-early/write-late): each FC half's weight tile
// (36.9KB) is loaded global->reg (9 int4/thread, bulk-pipelined) UNDER the
// previous compute phase, then written to sW after a barrier. Inner-loop
// weight reads become ds_read (~12cy) instead of scattered L2 loads (~200cy).
__global__ __launch_bounds__(256) void k_pmlp(
    const __hip_bfloat16* __restrict__ aob, const __hip_bfloat16* __restrict__ pwt,
    const float* __restrict__ pb, const float* __restrict__ x,
    const float* __restrict__ n2w, const float* __restrict__ n2b,
    const __hip_bfloat16* __restrict__ w1t, const float* __restrict__ b1,
    const __hip_bfloat16* __restrict__ w2t, const float* __restrict__ b2,
    float* __restrict__ out)
{
    __shared__ __align__(16) __hip_bfloat16 sBuf[64*200]; // sX(104) / sMid-half(200)
    __shared__ __align__(16) __hip_bfloat16 sW[192*104];  // w1-half [192][104] / w2-half [96][200]
    const int w = blockIdx.y;
    const int n0 = blockIdx.x * 64;
    const int tid = threadIdx.x;
    const int wv = tid >> 6, lane = tid & 63;
    const int l15 = lane & 15, h = lane >> 4;
    const int trow = wv*16 + l15;
    const int n = n0 + trow;
    const int nc = (n < NSEQ) ? n : (NSEQ-1);
    const int tok = tok_index(w, nc);

    // ---- issue L1: w1 half A (rows 0..191 of [384][96]) -> regs ----
    int4 sreg[9];
    #pragma unroll
    for (int r = 0; r < 9; ++r)
        sreg[r] = *(const int4*)(w1t + (size_t)(tid + r*256)*8);

    // ---- proj (MFMA) + input residual -> x1v regs ----
    float4 x1v[6];
    {
        I4S8 bm[3];
        #pragma unroll
        for (int ks = 0; ks < 3; ++ks)
            bm[ks].i = *(const int4*)(aob + ((size_t)w*NSEQ + nc)*CDIM + ks*32 + h*8);
        #pragma unroll
        for (int nt = 0; nt < 6; ++nt) {
            f32x4 acc = {0.f,0.f,0.f,0.f};
            #pragma unroll
            for (int ks = 0; ks < 3; ++ks) {
                I4S8 af;
                af.i = *(const int4*)(pwt + (size_t)(nt*16 + l15)*96 + ks*32 + h*8);
                acc = __builtin_amdgcn_mfma_f32_16x16x32_bf16(af.s, bm[ks].s, acc, 0, 0, 0);
            }
            const int col = nt*16 + 4*h;
            float4 xr = *(const float4*)&x[(size_t)tok*CDIM + col];
            float4 bb = *(const float4*)&pb[col];
            x1v[nt].x = xr.x + acc[0] + bb.x;
            x1v[nt].y = xr.y + acc[1] + bb.y;
            x1v[nt].z = xr.z + acc[2] + bb.z;
            x1v[nt].w = xr.w + acc[3] + bb.w;
        }
    }

    // ---- LN2 in-register -> sX (stride 104) ----
    {
        float s = 0.f, q = 0.f;
        #pragma unroll
        for (int nt = 0; nt < 6; ++nt) {
            s += (x1v[nt].x + x1v[nt].y) + (x1v[nt].z + x1v[nt].w);
            q += (x1v[nt].x*x1v[nt].x + x1v[nt].y*x1v[nt].y)
               + (x1v[nt].z*x1v[nt].z + x1v[nt].w*x1v[nt].w);
        }
        s += __shfl_xor(s, 16, 64); s += __shfl_xor(s, 32, 64);
        q += __shfl_xor(q, 16, 64); q += __shfl_xor(q, 32, 64);
        float mu = s * (1.0f/96.0f);
        float var = q * (1.0f/96.0f) - mu*mu;
        float rstd = rsqrtf(var + LN_EPS);
        #pragma unroll
        for (int nt = 0; nt < 6; ++nt) {
            const int col = nt*16 + 4*h;
            float4 nwv = *(const float4*)&n2w[col];
            float4 nbv = *(const float4*)&n2b[col];
            float a0 = (x1v[nt].x - mu)*rstd*nwv.x + nbv.x;
            float a1 = (x1v[nt].y - mu)*rstd*nwv.y + nbv.y;
            float a2 = (x1v[nt].z - mu)*rstd*nwv.z + nbv.z;
            float a3 = (x1v[nt].w - mu)*rstd*nwv.w + nbv.w;
            *(uint2*)&sBuf[trow*104 + col] = make_uint2(pk2(a0, a1), pk2(a2, a3));
        }
    }

    I4S8 bx[3];
    #pragma unroll
    for (int ks = 0; ks < 3; ++ks)
        bx[ks].i = *(const int4*)&sBuf[trow*104 + ks*32 + h*8];
    __syncthreads();                       // all sX reads done

    // ---- write L1 -> sW (w1 layout [192][104]); issue L2: w2 half A ----
    #pragma unroll
    for (int r = 0; r < 9; ++r) {
        int idx = tid + r*256;
        int row = idx / 12, cb = idx - row*12;        // 12 int4 per 96-col row
        *(int4*)&sW[row*104 + cb*8] = sreg[r];
    }
    #pragma unroll
    for (int r = 0; r < 9; ++r) {
        int idx = tid + r*256;
        int row = idx / 24, cb = idx - row*24;        // 24 int4 per 192-col row
        sreg[r] = *(const int4*)(w2t + (size_t)row*384 + cb*8);
    }
    __syncthreads();                       // sW = w1A ready

    f32x4 accs[6];
    #pragma unroll
    for (int nt = 0; nt < 6; ++nt) accs[nt] = (f32x4){0.f,0.f,0.f,0.f};

    // ---- FC1 half A (out cols 0..191) from sW + GELU -> sMid ----
    #pragma unroll 4
    for (int nt = 0; nt < 12; ++nt) {
        I4S8 af[3];
        #pragma unroll
        for (int ks = 0; ks < 3; ++ks)
            af[ks].i = *(const int4*)&sW[(nt*16 + l15)*104 + ks*32 + h*8];
        f32x4 acc = {0.f,0.f,0.f,0.f};
        #pragma unroll
        for (int ks = 0; ks < 3; ++ks)
            acc = __builtin_amdgcn_mfma_f32_16x16x32_bf16(af[ks].s, bx[ks].s, acc, 0, 0, 0);
        float4 bb = *(const float4*)&b1[nt*16 + 4*h];
        *(uint2*)&sBuf[trow*200 + nt*16 + 4*h] =
            make_uint2(pk2(gelu(acc[0]+bb.x), gelu(acc[1]+bb.y)),
                       pk2(gelu(acc[2]+bb.z), gelu(acc[3]+bb.w)));
    }
    __syncthreads();                       // all FC1A sW reads done

    // ---- write L2 -> sW (w2 layout [96][200]); issue L3: w1 half B ----
    #pragma unroll
    for (int r = 0; r < 9; ++r) {
        int idx = tid + r*256;
        int row = idx / 24, cb = idx - row*24;
        *(int4*)&sW[row*200 + cb*8] = sreg[r];
    }
    #pragma unroll
    for (int r = 0; r < 9; ++r)
        sreg[r] = *(const int4*)(w1t + (size_t)192*96 + (size_t)(tid + r*256)*8);
    __syncthreads();                       // sW = w2A ready

    // ---- FC2 partial A (K cols 0..191) from sW ----
    #pragma unroll 2
    for (int ks = 0; ks < 6; ++ks) {
        I4S8 bm; bm.i = *(const int4*)&sBuf[trow*200 + ks*32 + h*8];
        #pragma unroll
        for (int nt = 0; nt < 6; ++nt) {
            I4S8 af;
            af.i = *(const int4*)&sW[(nt*16 + l15)*200 + ks*32 + h*8];
            accs[nt] = __builtin_amdgcn_mfma_f32_16x16x32_bf16(af.s, bm.s, accs[nt], 0, 0, 0);
        }
    }
    __syncthreads();                       // all FC2A sW reads done

    // ---- write L3 -> sW (w1 layout); issue L4: w2 half B ----
    #pragma unroll
    for (int r = 0; r < 9; ++r) {
        int idx = tid + r*256;
        int row = idx / 12, cb = idx - row*12;
        *(int4*)&sW[row*104 + cb*8] = sreg[r];
    }
    #pragma unroll
    for (int r = 0; r < 9; ++r) {
        int idx = tid + r*256;
        int row = idx / 24, cb = idx - row*24;
        sreg[r] = *(const int4*)(w2t + (size_t)row*384 + 192 + cb*8);
    }
    __syncthreads();                       // sW = w1B ready

    // ---- FC1 half B (out cols 192..383) from sW -> overwrite sMid ----
    #pragma unroll 4
    for (int nt = 0; nt < 12; ++nt) {
        I4S8 af[3];
        #pragma unroll
        for (int ks = 0; ks < 3; ++ks)
            af[ks].i = *(const int4*)&sW[(nt*16 + l15)*104 + ks*32 + h*8];
        f32x4 acc = {0.f,0.f,0.f,0.f};
        #pragma unroll
        for (int ks = 0; ks < 3; ++ks)
            acc = __builtin_amdgcn_mfma_f32_16x16x32_bf16(af[ks].s, bx[ks].s, acc, 0, 0, 0);
        float4 bb = *(const float4*)&b1[(nt+12)*16 + 4*h];
        *(uint2*)&sBuf[trow*200 + nt*16 + 4*h] =
            make_uint2(pk2(gelu(acc[0]+bb.x), gelu(acc[1]+bb.y)),
                       pk2(gelu(acc[2]+bb.z), gelu(acc[3]+bb.w)));
    }
    __syncthreads();                       // all FC1B sW reads done

    // ---- write L4 -> sW (w2 layout) ----
    #pragma unroll
    for (int r = 0; r < 9; ++r) {
        int idx = tid + r*256;
        int row = idx / 24, cb = idx - row*24;
        *(int4*)&sW[row*200 + cb*8] = sreg[r];
    }
    __syncthreads();                       // sW = w2B ready

    // ---- FC2 partial B (K cols 192..383) from sW ----
    #pragma unroll 2
    for (int ks = 0; ks < 6; ++ks) {
        I4S8 bm; bm.i = *(const int4*)&sBuf[trow*200 + ks*32 + h*8];
        #pragma unroll
        for (int nt = 0; nt < 6; ++nt) {
            I4S8 af;
            af.i = *(const int4*)&sW[(nt*16 + l15)*200 + ks*32 + h*8];
            accs[nt] = __builtin_amdgcn_mfma_f32_16x16x32_bf16(af.s, bm.s, accs[nt], 0, 0, 0);
        }
    }

    // ---- residual (x1v regs) + bias -> out ----
    if (n < NSEQ) {
        #pragma unroll
        for (int nt = 0; nt < 6; ++nt) {
            const int col = nt*16 + 4*h;
            float4 bb = *(const float4*)&b2[col];
            float4 o;
            o.x = x1v[nt].x + accs[nt][0] + bb.x;
            o.y = x1v[nt].y + accs[nt][1] + bb.y;
            o.z = x1v[nt].z + accs[nt][2] + bb.z;
            o.w = x1v[nt].w + accs[nt][3] + bb.w;
            *(float4*)&out[(size_t)tok*CDIM + col] = o;
        }
    }
}

extern "C" void kernel_launch(void* const* d_in, const int* in_sizes, int n_in,
                              void* d_out, int out_size, void* d_ws, size_t ws_size,
                              hipStream_t stream) {
    const float* x    = (const float*)d_in[0];
    const float* mask = (const float*)d_in[1];
    const float* n1w  = (const float*)d_in[2];
    const float* n1b  = (const float*)d_in[3];
    const float* qkvw = (const float*)d_in[4];
    const float* qkvb = (const float*)d_in[5];
    const float* pw   = (const float*)d_in[6];
    const float* pb   = (const float*)d_in[7];
    const float* rpb  = (const float*)d_in[8];
    const float* n2w  = (const float*)d_in[9];
    const float* n2b  = (const float*)d_in[10];
    const float* w1   = (const float*)d_in[11];
    const float* b1   = (const float*)d_in[12];
    const float* w2   = (const float*)d_in[13];
    const float* b2   = (const float*)d_in[14];
    float* out = (float*)d_out;

    __hip_bfloat16* qb  = (__hip_bfloat16*)d_ws;
    __hip_bfloat16* kb  = qb + NTOT;
    __hip_bfloat16* vb  = kb + NTOT;
    __hip_bfloat16* aob = vb + NTOT;                       // [216][343][96] bf16
    float* bg = (float*)(aob + NTOT);                      // [3][343][343] f32
    __hip_bfloat16* w1t  = (__hip_bfloat16*)(bg + 352948); // [384][96]
    __hip_bfloat16* w2t  = w1t + 384*96;                   // [96][384]
    __hip_bfloat16* pwt  = w2t + 96*384;                   // [96][96]
    __hip_bfloat16* qkvt = pwt + 96*96;                    // [288][96]
    unsigned* mflag = (unsigned*)(qkvt + 288*96);          // [216]

    hipLaunchKernelGGL(k_wcast, dim3(864), dim3(384), 0, stream,
                       w1, w2, pw, qkvw, w1t, w2t, pwt, qkvt);
    hipLaunchKernelGGL(k_fused_prep, dim3(1296 + NWIN + NSEQ*3), dim3(256), 0, stream,
                       x, n1w, n1b, qkvt, qkvb, qb, kb, vb, mask, mflag, rpb, bg);
    hipLaunchKernelGGL(k_attn, dim3(NWIN*3), dim3(512), 0, stream,
                       qb, kb, vb, bg, mask, mflag, aob);
    hipLaunchKernelGGL(k_pmlp, dim3(6, NWIN), dim3(256), 0, stream,
                       aob, pwt, pb, x, n2w, n2b, w1t, b1, w2t, b2, out);
}

// Round 15
// 191.004 us; speedup vs baseline: 1.2069x; 1.2069x over previous
//
#include <hip/hip_runtime.h>
#include <hip/hip_bf16.h>
#include <math.h>

#define SDIM 42
#define CDIM 96
#define NTOK 74088          // 42^3
#define NWIN 216
#define NSEQ 343            // 7^3
#define NTOT 7112448        // NWIN*3*NSEQ*32 == NTOK*96
#define QK_SCALE 0.17677669529663687f
#define LN_EPS 1e-5f

typedef short short8 __attribute__((ext_vector_type(8)));
typedef float f32x4 __attribute__((ext_vector_type(4)));
typedef unsigned eu4 __attribute__((ext_vector_type(4)));
union I4S8 { int4 i; short8 s; };

__device__ __forceinline__ int tok_index(int w, int n) {
    int wq = w / 36;
    int wrem = w - wq * 36;
    int wh = wrem / 6;
    int ww = wrem - wh * 6;
    int ps = n / 49;
    int prem = n - ps * 49;
    int ph = prem / 7;
    int pw = prem - ph * 7;
    int s = wq * 7 + ps + 3; if (s >= SDIM) s -= SDIM;
    int h = wh * 7 + ph + 3; if (h >= SDIM) h -= SDIM;
    int c = ww * 7 + pw + 3; if (c >= SDIM) c -= SDIM;
    return (s * SDIM + h) * SDIM + c;
}

__device__ __forceinline__ unsigned pk2(float a, float b) {
    unsigned ua = (unsigned)__bfloat16_as_ushort(__float2bfloat16(a));
    unsigned ub = (unsigned)__bfloat16_as_ushort(__float2bfloat16(b));
    return ua | (ub << 16);
}

// Branch-free erf (Abramowitz-Stegun 7.1.26, |err| < 1.5e-7)
__device__ __forceinline__ float fast_erf(float x) {
    float ax = fabsf(x);
    float t = 1.0f / (1.0f + 0.3275911f * ax);
    float y = t*(0.254829592f + t*(-0.284496736f +
              t*(1.421413741f + t*(-1.453152027f + t*1.061405429f))));
    float r = 1.0f - y * __expf(-ax*ax);
    return copysignf(r, x);
}
__device__ __forceinline__ float gelu(float v) {
    return 0.5f * v * (1.0f + fast_erf(v * 0.70710678118654752f));
}

// ------------- Kernel 0b: transpose+cast all GEMM weights to bf16 -----------
__global__ __launch_bounds__(384) void k_wcast(
    const float* __restrict__ w1, const float* __restrict__ w2,
    const float* __restrict__ pw, const float* __restrict__ qkvw,
    __hip_bfloat16* __restrict__ w1t, __hip_bfloat16* __restrict__ w2t,
    __hip_bfloat16* __restrict__ pwt, __hip_bfloat16* __restrict__ qkvt)
{
    int b = blockIdx.x, t = threadIdx.x;
    if (b < 384) {
        if (t < 96) w1t[(size_t)b*96 + t] = __float2bfloat16(w1[(size_t)t*384 + b]);
    } else if (b < 480) {
        int r = b - 384;
        w2t[(size_t)r*384 + t] = __float2bfloat16(w2[(size_t)t*96 + r]);
    } else if (b < 576) {
        int r = b - 480;
        if (t < 96) pwt[(size_t)r*96 + t] = __float2bfloat16(pw[(size_t)t*96 + r]);
    } else {
        int c = b - 576;
        if (t < 96) qkvt[(size_t)c*96 + t] = __float2bfloat16(qkvw[(size_t)t*288 + c]);
    }
}

// --- Kernel 1 (fused): LN1+gather+QKV GEMM | mask scan | bias table ---------
__global__ __launch_bounds__(256) void k_fused_prep(
    const float* __restrict__ x,
    const float* __restrict__ n1w, const float* __restrict__ n1b,
    const __hip_bfloat16* __restrict__ qkvt, const float* __restrict__ qkvb,
    __hip_bfloat16* __restrict__ qb, __hip_bfloat16* __restrict__ kb,
    __hip_bfloat16* __restrict__ vb,
    const float* __restrict__ mask, unsigned* __restrict__ mflag,
    const float* __restrict__ rpb, float* __restrict__ bg)
{
    __shared__ __align__(16) __hip_bfloat16 sX[64*104];
    __shared__ unsigned sFlag;
    const int b = blockIdx.x;
    const int tid = threadIdx.x;

    if (b >= 1296 + NWIN) {
        // ---- bias table ----
        const int p = b - (1296 + NWIN);
        const int m = p % NSEQ, hh = p / NSEQ;
        const int a0 = m / 49, ar = m - a0*49, a1 = ar / 7, a2 = ar - a1*7;
        for (int n = tid; n < NSEQ; n += 256) {
            int b0 = n / 49, br = n - b0*49, b1 = br / 7, b2 = br - b1*7;
            int idx = (a0 - b0 + 6)*20 + (a1 - b1 + 6)*13 + (a2 - b2 + 6);
            bg[((size_t)hh*NSEQ + m)*NSEQ + n] = rpb[idx*3 + hh];
        }
        return;
    }
    if (b >= 1296) {
        // ---- mask scan (NT loads: 101MB read-once stream) ----
        const int w = b - 1296;
        if (tid == 0) sFlag = 0;
        __syncthreads();
        const unsigned* p = (const unsigned*)(mask + (size_t)w * NSEQ * NSEQ);
        unsigned acc = 0;
        const eu4* p4 = (const eu4*)p;
        for (int i = tid; i < (NSEQ*NSEQ)/4; i += 256) {
            eu4 v = __builtin_nontemporal_load(p4 + i);
            acc |= (v[0] << 1) | (v[1] << 1) | (v[2] << 1) | (v[3] << 1);
        }
        if (tid == 0) acc |= (p[NSEQ*NSEQ - 1] << 1);
        if (__any(acc != 0) && (tid & 63) == 0) atomicOr(&sFlag, 1u);
        __syncthreads();
        if (tid == 0) mflag[w] = sFlag;
        return;
    }

    // ---- LN1 + gather + QKV GEMM ----
    const int w  = b / 6;
    const int n0 = (b - w*6) * 64;
    const int g = tid >> 5, l = tid & 31;
    {
        const float lw0 = n1w[l], lw1 = n1w[l+32], lw2 = n1w[l+64];
        const float lb0 = n1b[l], lb1 = n1b[l+32], lb2 = n1b[l+64];
        for (int rr = 0; rr < 8; ++rr) {
            int row = g * 8 + rr;
            int n = n0 + row;
            if (n < NSEQ) {
                const float* xr = x + (size_t)tok_index(w, n) * CDIM;
                float x0 = __builtin_nontemporal_load(xr + l);
                float x1 = __builtin_nontemporal_load(xr + l + 32);
                float x2 = __builtin_nontemporal_load(xr + l + 64);
                float s = x0 + x1 + x2;
                #pragma unroll
                for (int m = 16; m; m >>= 1) s += __shfl_xor(s, m, 32);
                float mu = s * (1.0f/96.0f);
                float d0 = x0-mu, d1 = x1-mu, d2 = x2-mu;
                float vv = d0*d0 + d1*d1 + d2*d2;
                #pragma unroll
                for (int m = 16; m; m >>= 1) vv += __shfl_xor(vv, m, 32);
                float rstd = rsqrtf(vv * (1.0f/96.0f) + LN_EPS);
                sX[row*104 + l]    = __float2bfloat16(d0 * rstd * lw0 + lb0);
                sX[row*104 + l+32] = __float2bfloat16(d1 * rstd * lw1 + lb1);
                sX[row*104 + l+64] = __float2bfloat16(d2 * rstd * lw2 + lb2);
            } else {
                sX[row*104 + l]    = __float2bfloat16(0.f);
                sX[row*104 + l+32] = __float2bfloat16(0.f);
                sX[row*104 + l+64] = __float2bfloat16(0.f);
            }
        }
    }
    __syncthreads();

    const int wv = tid >> 6, lane = tid & 63;
    const int l15 = lane & 15, h = lane >> 4;
    const int trow = wv*16 + l15;
    const int n = n0 + trow;

    I4S8 bx[3];
    #pragma unroll
    for (int ks = 0; ks < 3; ++ks)
        bx[ks].i = *(const int4*)&sX[trow*104 + ks*32 + h*8];

    for (int nt = 0; nt < 18; ++nt) {
        f32x4 acc = {0.f,0.f,0.f,0.f};
        #pragma unroll
        for (int ks = 0; ks < 3; ++ks) {
            I4S8 af;
            af.i = *(const int4*)(qkvt + (size_t)(nt*16 + l15)*96 + ks*32 + h*8);
            acc = __builtin_amdgcn_mfma_f32_16x16x32_bf16(af.s, bx[ks].s, acc, 0, 0, 0);
        }
        if (n < NSEQ) {
            const int colbase = nt*16 + 4*h;          // [0,288)
            const int sel = colbase / 96;
            const int rem = colbase - sel*96;
            const int head = rem >> 5, d0 = rem & 31;
            float4 bb = *(const float4*)&qkvb[colbase];
            float v0 = acc[0] + bb.x, v1 = acc[1] + bb.y;
            float v2 = acc[2] + bb.z, v3 = acc[3] + bb.w;
            if (sel == 0) { v0 *= QK_SCALE; v1 *= QK_SCALE; v2 *= QK_SCALE; v3 *= QK_SCALE; }
            __hip_bfloat16* dst = (sel == 0 ? qb : (sel == 1 ? kb : vb));
            *(uint2*)&dst[(((size_t)w*3 + head)*NSEQ + n)*32 + d0] =
                make_uint2(pk2(v0, v1), pk2(v2, v3));
        }
    }
}

// ------- Kernel 2: windowed attention via MFMA (streaming, no-max) ----------
template<bool UM>
__device__ __forceinline__ void attn_qloop(
    const __hip_bfloat16* __restrict__ qb, const float* __restrict__ bg,
    const float* __restrict__ mask, __hip_bfloat16* __restrict__ aob,
    const __hip_bfloat16* sK, const __hip_bfloat16* sVT,
    size_t base, int w, int head, int wid, int l15, int h)
{
    for (int mt = wid; mt < 22; mt += 8) {
        const int m = mt*16 + l15;
        const int mc = (m < NSEQ) ? m : (NSEQ-1);

        I4S8 qf;
        qf.i = *(const int4*)(qb + base + (size_t)mc*32 + h*8);

        const float* mrow = mask + ((size_t)w*NSEQ + mc)*NSEQ;
        const float* brow = bg   + ((size_t)head*NSEQ + mc)*NSEQ;

        float lsum = 0.f;
        f32x4 acc0 = {0.f,0.f,0.f,0.f}, acc1 = {0.f,0.f,0.f,0.f};

        auto step = [&](int t, float4 mkA, float4 bsA, float4 mkB, float4 bsB) {
            float p[8];
            {
                I4S8 kf;
                kf.i = *(const int4*)&sK[(t*16 + l15)*32 + h*8];
                f32x4 st = __builtin_amdgcn_mfma_f32_16x16x32_bf16(
                    kf.s, qf.s, (f32x4){0.f,0.f,0.f,0.f}, 0, 0, 0);
                if constexpr (UM) {
                    p[0] = __expf(st[0] + mkA.x + bsA.x);
                    p[1] = __expf(st[1] + mkA.y + bsA.y);
                    p[2] = __expf(st[2] + mkA.z + bsA.z);
                    p[3] = __expf(st[3] + mkA.w + bsA.w);
                } else {
                    p[0] = __expf(st[0] + bsA.x);
                    p[1] = __expf(st[1] + bsA.y);
                    p[2] = __expf(st[2] + bsA.z);
                    p[3] = __expf(st[3] + bsA.w);
                }
                lsum += (p[0] + p[1]) + (p[2] + p[3]);
            }
            {
                I4S8 kf;
                kf.i = *(const int4*)&sK[((t+1)*16 + l15)*32 + h*8];
                f32x4 st = __builtin_amdgcn_mfma_f32_16x16x32_bf16(
                    kf.s, qf.s, (f32x4){0.f,0.f,0.f,0.f}, 0, 0, 0);
                if constexpr (UM) {
                    p[4] = __expf(st[0] + mkB.x + bsB.x);
                    p[5] = __expf(st[1] + mkB.y + bsB.y);
                    p[6] = __expf(st[2] + mkB.z + bsB.z);
                    p[7] = __expf(st[3] + mkB.w + bsB.w);
                } else {
                    p[4] = __expf(st[0] + bsB.x);
                    p[5] = __expf(st[1] + bsB.y);
                    p[6] = __expf(st[2] + bsB.z);
                    p[7] = __expf(st[3] + bsB.w);
                }
                lsum += (p[4] + p[5]) + (p[6] + p[7]);
            }
            I4S8 pf;
            pf.i = make_int4(pk2(p[0], p[1]), pk2(p[2], p[3]),
                             pk2(p[4], p[5]), pk2(p[6], p[7]));
            const int vcol = t*16 + 4*h;
            uint2 va0 = *(const uint2*)&sVT[(l15     )*372 + vcol];
            uint2 vb0 = *(const uint2*)&sVT[(l15     )*372 + vcol + 16];
            uint2 va1 = *(const uint2*)&sVT[(16 + l15)*372 + vcol];
            uint2 vb1 = *(const uint2*)&sVT[(16 + l15)*372 + vcol + 16];
            I4S8 vf0; vf0.i = make_int4(va0.x, va0.y, vb0.x, vb0.y);
            I4S8 vf1; vf1.i = make_int4(va1.x, va1.y, vb1.x, vb1.y);
            acc0 = __builtin_amdgcn_mfma_f32_16x16x32_bf16(vf0.s, pf.s, acc0, 0, 0, 0);
            acc1 = __builtin_amdgcn_mfma_f32_16x16x32_bf16(vf1.s, pf.s, acc1, 0, 0, 0);
        };

        const float4 z4 = {0.f,0.f,0.f,0.f};
        float4 mkA = UM ? *(const float4*)&mrow[4*h]      : z4;
        float4 bsA =      *(const float4*)&brow[4*h];
        float4 mkB = UM ? *(const float4*)&mrow[16 + 4*h] : z4;
        float4 bsB =      *(const float4*)&brow[16 + 4*h];

        #pragma unroll 1
        for (int c = 0; c < 9; ++c) {
            const int nb = (2*c + 2)*16 + 4*h;
            float4 nmkA = UM ? *(const float4*)&mrow[nb]      : z4;
            float4 nbsA =      *(const float4*)&brow[nb];
            float4 nmkB = UM ? *(const float4*)&mrow[nb + 16] : z4;
            float4 nbsB =      *(const float4*)&brow[nb + 16];
            step(2*c, mkA, bsA, mkB, bsB);
            mkA = nmkA; bsA = nbsA; mkB = nmkB; bsB = nbsB;
        }

        {
            float4 nmkA = UM ? *(const float4*)&mrow[320 + 4*h] : z4;
            float4 nbsA =      *(const float4*)&brow[320 + 4*h];
            float4 nmkB = z4, nbsB;
            {
                const int nb = 336 + 4*h;
                int i0 = nb,   c0 = (i0 < NSEQ) ? i0 : (NSEQ-1);
                int i1 = nb+1, c1 = (i1 < NSEQ) ? i1 : (NSEQ-1);
                int i2 = nb+2, c2 = (i2 < NSEQ) ? i2 : (NSEQ-1);
                int i3 = nb+3, c3 = (i3 < NSEQ) ? i3 : (NSEQ-1);
                if constexpr (UM) {
                    nmkB.x = mrow[c0]; nmkB.y = mrow[c1];
                    nmkB.z = mrow[c2]; nmkB.w = mrow[c3];
                }
                nbsB.x = brow[c0]; nbsB.y = brow[c1];
                nbsB.z = brow[c2]; nbsB.w = brow[c3];
            }
            step(18, mkA, bsA, mkB, bsB);
            mkA = nmkA; bsA = nbsA; mkB = nmkB; bsB = nbsB;
        }

        {
            float p[8];
            {
                I4S8 kf;
                kf.i = *(const int4*)&sK[(20*16 + l15)*32 + h*8];
                f32x4 st = __builtin_amdgcn_mfma_f32_16x16x32_bf16(
                    kf.s, qf.s, (f32x4){0.f,0.f,0.f,0.f}, 0, 0, 0);
                if constexpr (UM) {
                    p[0] = __expf(st[0] + mkA.x + bsA.x);
                    p[1] = __expf(st[1] + mkA.y + bsA.y);
                    p[2] = __expf(st[2] + mkA.z + bsA.z);
                    p[3] = __expf(st[3] + mkA.w + bsA.w);
                } else {
                    p[0] = __expf(st[0] + bsA.x);
                    p[1] = __expf(st[1] + bsA.y);
                    p[2] = __expf(st[2] + bsA.z);
                    p[3] = __expf(st[3] + bsA.w);
                }
                lsum += (p[0] + p[1]) + (p[2] + p[3]);
            }
            {
                I4S8 kf;
                kf.i = *(const int4*)&sK[(21*16 + l15)*32 + h*8];
                f32x4 st = __builtin_amdgcn_mfma_f32_16x16x32_bf16(
                    kf.s, qf.s, (f32x4){0.f,0.f,0.f,0.f}, 0, 0, 0);
                float sb[4];
                if constexpr (UM) {
                    sb[0] = mkB.x + bsB.x; sb[1] = mkB.y + bsB.y;
                    sb[2] = mkB.z + bsB.z; sb[3] = mkB.w + bsB.w;
                } else {
                    sb[0] = bsB.x; sb[1] = bsB.y; sb[2] = bsB.z; sb[3] = bsB.w;
                }
                const int nb = 336 + 4*h;
                #pragma unroll
                for (int r = 0; r < 4; ++r) {
                    const int nn = nb + r;
                    float e = 0.f;
                    if (nn < NSEQ) e = __expf(st[r] + sb[r]);
                    p[4+r] = e; lsum += e;
                }
            }
            I4S8 pf;
            pf.i = make_int4(pk2(p[0], p[1]), pk2(p[2], p[3]),
                             pk2(p[4], p[5]), pk2(p[6], p[7]));
            const int vcol = 320 + 4*h;                // cols 343.. are zeroed
            uint2 va0 = *(const uint2*)&sVT[(l15     )*372 + vcol];
            uint2 vb0 = *(const uint2*)&sVT[(l15     )*372 + vcol + 16];
            uint2 va1 = *(const uint2*)&sVT[(16 + l15)*372 + vcol];
            uint2 vb1 = *(const uint2*)&sVT[(16 + l15)*372 + vcol + 16];
            I4S8 vf0; vf0.i = make_int4(va0.x, va0.y, vb0.x, vb0.y);
            I4S8 vf1; vf1.i = make_int4(va1.x, va1.y, vb1.x, vb1.y);
            acc0 = __builtin_amdgcn_mfma_f32_16x16x32_bf16(vf0.s, pf.s, acc0, 0, 0, 0);
            acc1 = __builtin_amdgcn_mfma_f32_16x16x32_bf16(vf1.s, pf.s, acc1, 0, 0, 0);
        }

        lsum += __shfl_xor(lsum, 16, 64);
        lsum += __shfl_xor(lsum, 32, 64);
        const float inv = 1.0f / lsum;

        if (m < NSEQ) {
            __hip_bfloat16* orow = &aob[((size_t)w*NSEQ + m)*CDIM + head*32];
            *(uint2*)&orow[4*h] =
                make_uint2(pk2(acc0[0]*inv, acc0[1]*inv), pk2(acc0[2]*inv, acc0[3]*inv));
            *(uint2*)&orow[16 + 4*h] =
                make_uint2(pk2(acc1[0]*inv, acc1[1]*inv), pk2(acc1[2]*inv, acc1[3]*inv));
        }
    }
}

__global__ __launch_bounds__(512) void k_attn(
    const __hip_bfloat16* __restrict__ qb, const __hip_bfloat16* __restrict__ kb,
    const __hip_bfloat16* __restrict__ vb, const float* __restrict__ bg,
    const float* __restrict__ mask, const unsigned* __restrict__ mflag,
    __hip_bfloat16* __restrict__ aob)
{
    __shared__ __hip_bfloat16 sK[352*32];      // K rows [343][32], 64B stride
    __shared__ __hip_bfloat16 sVT[32*372];     // V^T [32][343], stride 372
    const int tid = threadIdx.x;
    const int v = blockIdx.x;
    const int xcd = v & 7, tt = v >> 3;
    const int j = tt / 3, head = tt - 3*j;
    const int w = xcd + 8*j;
    const size_t base = ((size_t)w*3 + head) * (NSEQ*32);

    {
        const int4* ksrc = (const int4*)(kb + base);
        for (int i = tid; i < NSEQ*4; i += 512) {
            int row = i >> 2, q = i & 3;
            *(int4*)&sK[row*32 + q*8] = ksrc[i];
        }
        const int4* vsrc = (const int4*)(vb + base);
        for (int i = tid; i < NSEQ*4; i += 512) {
            int n = i >> 2, dc = i & 3;
            int4 t = vsrc[i];
            const __hip_bfloat16* tp = (const __hip_bfloat16*)&t;
            #pragma unroll
            for (int k2 = 0; k2 < 8; ++k2) sVT[(dc*8 + k2)*372 + n] = tp[k2];
        }
        for (int i = tid; i < 32*29; i += 512) {   // zero cols 343..371
            int d = i / 29, n = NSEQ + (i - d*29);
            sVT[d*372 + n] = __float2bfloat16(0.f);
        }
    }
    __syncthreads();

    const int wid = tid >> 6, lane = tid & 63;
    const int l15 = lane & 15, h = lane >> 4;

    if (mflag[w] == 0)
        attn_qloop<false>(qb, bg, mask, aob, sK, sVT, base, w, head, wid, l15, h);
    else
        attn_qloop<true>(qb, bg, mask, aob, sK, sVT, base, w, head, wid, l15, h);
}

// ---- Kernel 3: fused proj+residual+LN2+FC1+GELU+FC2+residual ---------------
// Quarter-staged weights: 19.2KB sW refilled 9x/tile (pwt, 4x w1-q, 4x w2-q)
// via immediate load->LDS (no registers held across compute -> no spill).
// sBuf [64][104] serves sX AND sMid-quarter (same stride -> wave-local rows,
// no barriers except around sW stages). LDS 32.5KB -> 5 blocks/CU.
__global__ __launch_bounds__(256) void k_pmlp(
    const __hip_bfloat16* __restrict__ aob, const __hip_bfloat16* __restrict__ pwt,
    const float* __restrict__ pb, const float* __restrict__ x,
    const float* __restrict__ n2w, const float* __restrict__ n2b,
    const __hip_bfloat16* __restrict__ w1t, const float* __restrict__ b1,
    const __hip_bfloat16* __restrict__ w2t, const float* __restrict__ b2,
    float* __restrict__ out)
{
    __shared__ __align__(16) __hip_bfloat16 sBuf[64*104];  // sX / sMid-quarter
    __shared__ __align__(16) __hip_bfloat16 sW[96*100];    // staged weight quarter
    const int w = blockIdx.y;
    const int n0 = blockIdx.x * 64;
    const int tid = threadIdx.x;
    const int wv = tid >> 6, lane = tid & 63;
    const int l15 = lane & 15, h = lane >> 4;
    const int trow = wv*16 + l15;
    const int n = n0 + trow;
    const int nc = (n < NSEQ) ? n : (NSEQ-1);
    const int tok = tok_index(w, nc);

    // ---- stage pwt -> sW (18KB coalesced; 4.5 int4/thread) ----
    for (int i = tid; i < 1152; i += 256) {
        int row = i / 12, cb = i - row*12;
        int4 t = *(const int4*)(pwt + (size_t)row*96 + cb*8);
        *(int4*)&sW[row*100 + cb*8] = t;
    }
    I4S8 bm[3];
    #pragma unroll
    for (int ks = 0; ks < 3; ++ks)
        bm[ks].i = *(const int4*)(aob + ((size_t)w*NSEQ + nc)*CDIM + ks*32 + h*8);
    __syncthreads();

    // ---- proj (MFMA from sW) + input residual -> x1v regs ----
    float4 x1v[6];
    #pragma unroll
    for (int nt = 0; nt < 6; ++nt) {
        f32x4 acc = {0.f,0.f,0.f,0.f};
        #pragma unroll
        for (int ks = 0; ks < 3; ++ks) {
            I4S8 af;
            af.i = *(const int4*)&sW[(nt*16 + l15)*100 + ks*32 + h*8];
            acc = __builtin_amdgcn_mfma_f32_16x16x32_bf16(af.s, bm[ks].s, acc, 0, 0, 0);
        }
        const int col = nt*16 + 4*h;
        float4 xr = *(const float4*)&x[(size_t)tok*CDIM + col];
        float4 bb = *(const float4*)&pb[col];
        x1v[nt].x = xr.x + acc[0] + bb.x;
        x1v[nt].y = xr.y + acc[1] + bb.y;
        x1v[nt].z = xr.z + acc[2] + bb.z;
        x1v[nt].w = xr.w + acc[3] + bb.w;
    }

    // ---- LN2 in-register -> sBuf (sX, stride 104) ----
    {
        float s = 0.f, q = 0.f;
        #pragma unroll
        for (int nt = 0; nt < 6; ++nt) {
            s += (x1v[nt].x + x1v[nt].y) + (x1v[nt].z + x1v[nt].w);
            q += (x1v[nt].x*x1v[nt].x + x1v[nt].y*x1v[nt].y)
               + (x1v[nt].z*x1v[nt].z + x1v[nt].w*x1v[nt].w);
        }
        s += __shfl_xor(s, 16, 64); s += __shfl_xor(s, 32, 64);
        q += __shfl_xor(q, 16, 64); q += __shfl_xor(q, 32, 64);
        float mu = s * (1.0f/96.0f);
        float var = q * (1.0f/96.0f) - mu*mu;
        float rstd = rsqrtf(var + LN_EPS);
        #pragma unroll
        for (int nt = 0; nt < 6; ++nt) {
            const int col = nt*16 + 4*h;
            float4 nwv = *(const float4*)&n2w[col];
            float4 nbv = *(const float4*)&n2b[col];
            float a0 = (x1v[nt].x - mu)*rstd*nwv.x + nbv.x;
            float a1 = (x1v[nt].y - mu)*rstd*nwv.y + nbv.y;
            float a2 = (x1v[nt].z - mu)*rstd*nwv.z + nbv.z;
            float a3 = (x1v[nt].w - mu)*rstd*nwv.w + nbv.w;
            *(uint2*)&sBuf[trow*104 + col] = make_uint2(pk2(a0, a1), pk2(a2, a3));
        }
    }

    // ---- B-frags for FC1 from sX (wave-local rows; in-wave order safe) ----
    I4S8 bx[3];
    #pragma unroll
    for (int ks = 0; ks < 3; ++ks)
        bx[ks].i = *(const int4*)&sBuf[trow*104 + ks*32 + h*8];

    f32x4 accs[6];
    #pragma unroll
    for (int nt = 0; nt < 6; ++nt) accs[nt] = (f32x4){0.f,0.f,0.f,0.f};

    // ---- 4 K/N quarters: stage w1q -> FC1q -> stage w2q -> FC2q ----
    #pragma unroll 1
    for (int q = 0; q < 4; ++q) {
        __syncthreads();                      // prior sW reads done
        for (int i = tid; i < 1152; i += 256) {
            int row = i / 12, cb = i - row*12;
            int4 t = *(const int4*)(w1t + (size_t)(q*96 + row)*96 + cb*8);
            *(int4*)&sW[row*100 + cb*8] = t;
        }
        __syncthreads();                      // w1q visible

        // FC1 quarter: out cols q*96..q*96+95 -> sBuf (sMid, stride 104)
        #pragma unroll
        for (int ntl = 0; ntl < 6; ++ntl) {
            I4S8 af[3];
            #pragma unroll
            for (int ks = 0; ks < 3; ++ks)
                af[ks].i = *(const int4*)&sW[(ntl*16 + l15)*100 + ks*32 + h*8];
            f32x4 acc = {0.f,0.f,0.f,0.f};
            #pragma unroll
            for (int ks = 0; ks < 3; ++ks)
                acc = __builtin_amdgcn_mfma_f32_16x16x32_bf16(af[ks].s, bx[ks].s, acc, 0, 0, 0);
            float4 bb = *(const float4*)&b1[q*96 + ntl*16 + 4*h];
            *(uint2*)&sBuf[trow*104 + ntl*16 + 4*h] =
                make_uint2(pk2(gelu(acc[0]+bb.x), gelu(acc[1]+bb.y)),
                           pk2(gelu(acc[2]+bb.z), gelu(acc[3]+bb.w)));
        }

        __syncthreads();                      // FC1q sW reads done
        for (int i = tid; i < 1152; i += 256) {
            int row = i / 12, cb = i - row*12;
            int4 t = *(const int4*)(w2t + (size_t)row*384 + q*96 + cb*8);
            *(int4*)&sW[row*100 + cb*8] = t;
        }
        __syncthreads();                      // w2q visible

        // FC2 quarter: K cols q*96..q*96+95 from sMid (wave-local)
        #pragma unroll
        for (int ksl = 0; ksl < 3; ++ksl) {
            I4S8 bmq;
            bmq.i = *(const int4*)&sBuf[trow*104 + ksl*32 + h*8];
            #pragma unroll
            for (int nt = 0; nt < 6; ++nt) {
                I4S8 af;
                af.i = *(const int4*)&sW[(nt*16 + l15)*100 + ksl*32 + h*8];
                accs[nt] = __builtin_amdgcn_mfma_f32_16x16x32_bf16(af.s, bmq.s, accs[nt], 0, 0, 0);
            }
        }
    }

    // ---- residual (x1v regs) + bias -> out ----
    if (n < NSEQ) {
        #pragma unroll
        for (int nt = 0; nt < 6; ++nt) {
            const int col = nt*16 + 4*h;
            float4 bb = *(const float4*)&b2[col];
            float4 o;
            o.x = x1v[nt].x + accs[nt][0] + bb.x;
            o.y = x1v[nt].y + accs[nt][1] + bb.y;
            o.z = x1v[nt].z + accs[nt][2] + bb.z;
            o.w = x1v[nt].w + accs[nt][3] + bb.w;
            *(float4*)&out[(size_t)tok*CDIM + col] = o;
        }
    }
}

extern "C" void kernel_launch(void* const* d_in, const int* in_sizes, int n_in,
                              void* d_out, int out_size, void* d_ws, size_t ws_size,
                              hipStream_t stream) {
    const float* x    = (const float*)d_in[0];
    const float* mask = (const float*)d_in[1];
    const float* n1w  = (const float*)d_in[2];
    const float* n1b  = (const float*)d_in[3];
    const float* qkvw = (const float*)d_in[4];
    const float* qkvb = (const float*)d_in[5];
    const float* pw   = (const float*)d_in[6];
    const float* pb   = (const float*)d_in[7];
    const float* rpb  = (const float*)d_in[8];
    const float* n2w  = (const float*)d_in[9];
    const float* n2b  = (const float*)d_in[10];
    const float* w1   = (const float*)d_in[11];
    const float* b1   = (const float*)d_in[12];
    const float* w2   = (const float*)d_in[13];
    const float* b2   = (const float*)d_in[14];
    float* out = (float*)d_out;

    __hip_bfloat16* qb  = (__hip_bfloat16*)d_ws;
    __hip_bfloat16* kb  = qb + NTOT;
    __hip_bfloat16* vb  = kb + NTOT;
    __hip_bfloat16* aob = vb + NTOT;                       // [216][343][96] bf16
    float* bg = (float*)(aob + NTOT);                      // [3][343][343] f32
    __hip_bfloat16* w1t  = (__hip_bfloat16*)(bg + 352948); // [384][96]
    __hip_bfloat16* w2t  = w1t + 384*96;                   // [96][384]
    __hip_bfloat16* pwt  = w2t + 96*384;                   // [96][96]
    __hip_bfloat16* qkvt = pwt + 96*96;                    // [288][96]
    unsigned* mflag = (unsigned*)(qkvt + 288*96);          // [216]

    hipLaunchKernelGGL(k_wcast, dim3(864), dim3(384), 0, stream,
                       w1, w2, pw, qkvw, w1t, w2t, pwt, qkvt);
    hipLaunchKernelGGL(k_fused_prep, dim3(1296 + NWIN + NSEQ*3), dim3(256), 0, stream,
                       x, n1w, n1b, qkvt, qkvb, qb, kb, vb, mask, mflag, rpb, bg);
    hipLaunchKernelGGL(k_attn, dim3(NWIN*3), dim3(512), 0, stream,
                       qb, kb, vb, bg, mask, mflag, aob);
    hipLaunchKernelGGL(k_pmlp, dim3(6, NWIN), dim3(256), 0, stream,
                       aob, pwt, pb, x, n2w, n2b, w1t, b1, w2t, b2, out);
}

// Round 16
// 164.324 us; speedup vs baseline: 1.4028x; 1.1624x over previous
//
#include <hip/hip_runtime.h>
#include <hip/hip_bf16.h>
#include <math.h>

#define SDIM 42
#define CDIM 96
#define NTOK 74088          // 42^3
#define NWIN 216
#define NSEQ 343            // 7^3
#define NTOT 7112448        // NWIN*3*NSEQ*32 == NTOK*96
#define QK_SCALE 0.17677669529663687f
#define LN_EPS 1e-5f

typedef short short8 __attribute__((ext_vector_type(8)));
typedef float f32x4 __attribute__((ext_vector_type(4)));
typedef unsigned eu4 __attribute__((ext_vector_type(4)));
union I4S8 { int4 i; short8 s; };

__device__ __forceinline__ int tok_index(int w, int n) {
    int wq = w / 36;
    int wrem = w - wq * 36;
    int wh = wrem / 6;
    int ww = wrem - wh * 6;
    int ps = n / 49;
    int prem = n - ps * 49;
    int ph = prem / 7;
    int pw = prem - ph * 7;
    int s = wq * 7 + ps + 3; if (s >= SDIM) s -= SDIM;
    int h = wh * 7 + ph + 3; if (h >= SDIM) h -= SDIM;
    int c = ww * 7 + pw + 3; if (c >= SDIM) c -= SDIM;
    return (s * SDIM + h) * SDIM + c;
}

__device__ __forceinline__ unsigned pk2(float a, float b) {
    unsigned ua = (unsigned)__bfloat16_as_ushort(__float2bfloat16(a));
    unsigned ub = (unsigned)__bfloat16_as_ushort(__float2bfloat16(b));
    return ua | (ub << 16);
}

// Branch-free erf (Abramowitz-Stegun 7.1.26, |err| < 1.5e-7)
__device__ __forceinline__ float fast_erf(float x) {
    float ax = fabsf(x);
    float t = 1.0f / (1.0f + 0.3275911f * ax);
    float y = t*(0.254829592f + t*(-0.284496736f +
              t*(1.421413741f + t*(-1.453152027f + t*1.061405429f))));
    float r = 1.0f - y * __expf(-ax*ax);
    return copysignf(r, x);
}
__device__ __forceinline__ float gelu(float v) {
    return 0.5f * v * (1.0f + fast_erf(v * 0.70710678118654752f));
}

// ------- Kernel 0b: transpose+cast all GEMM weights to bf16; zero mflag -----
__global__ __launch_bounds__(384) void k_wcast(
    const float* __restrict__ w1, const float* __restrict__ w2,
    const float* __restrict__ pw, const float* __restrict__ qkvw,
    __hip_bfloat16* __restrict__ w1t, __hip_bfloat16* __restrict__ w2t,
    __hip_bfloat16* __restrict__ pwt, __hip_bfloat16* __restrict__ qkvt,
    unsigned* __restrict__ mflag)
{
    int b = blockIdx.x, t = threadIdx.x;
    if (b < 384) {
        if (t < 96) w1t[(size_t)b*96 + t] = __float2bfloat16(w1[(size_t)t*384 + b]);
    } else if (b < 480) {
        int r = b - 384;
        w2t[(size_t)r*384 + t] = __float2bfloat16(w2[(size_t)t*96 + r]);
    } else if (b < 576) {
        int r = b - 480;
        if (t < 96) pwt[(size_t)r*96 + t] = __float2bfloat16(pw[(size_t)t*96 + r]);
    } else if (b < 864) {
        int c = b - 576;
        if (t < 96) qkvt[(size_t)c*96 + t] = __float2bfloat16(qkvw[(size_t)t*288 + c]);
    } else {
        if (t < NWIN) mflag[t] = 0;
    }
}

// --- Kernel 1 (fused): LN1+gather+QKV GEMM | mask scan (4x) | bias table ----
__global__ __launch_bounds__(256) void k_fused_prep(
    const float* __restrict__ x,
    const float* __restrict__ n1w, const float* __restrict__ n1b,
    const __hip_bfloat16* __restrict__ qkvt, const float* __restrict__ qkvb,
    __hip_bfloat16* __restrict__ qb, __hip_bfloat16* __restrict__ kb,
    __hip_bfloat16* __restrict__ vb,
    const float* __restrict__ mask, unsigned* __restrict__ mflag,
    const float* __restrict__ rpb, float* __restrict__ bg)
{
    __shared__ __align__(16) __hip_bfloat16 sX[64*104];
    const int b = blockIdx.x;
    const int tid = threadIdx.x;

    if (b >= 2160) {
        // ---- bias table ----
        const int p = b - 2160;
        const int m = p % NSEQ, hh = p / NSEQ;
        const int a0 = m / 49, ar = m - a0*49, a1 = ar / 7, a2 = ar - a1*7;
        for (int n = tid; n < NSEQ; n += 256) {
            int b0 = n / 49, br = n - b0*49, b1 = br / 7, b2 = br - b1*7;
            int idx = (a0 - b0 + 6)*20 + (a1 - b1 + 6)*13 + (a2 - b2 + 6);
            bg[((size_t)hh*NSEQ + m)*NSEQ + n] = rpb[idx*3 + hh];
        }
        return;
    }
    if (b >= 1296) {
        // ---- mask scan: 4 sub-blocks per window (NT loads; 101MB stream) ----
        const int idx = b - 1296;
        const int w = idx >> 2, part = idx & 3;
        const unsigned* p = (const unsigned*)(mask + (size_t)w * NSEQ * NSEQ);
        const eu4* p4 = (const eu4*)p;
        unsigned acc = 0;
        const int lo = part * 7353, hi = lo + 7353;   // 4*7353 = 29412 uint4
        for (int i = lo + tid; i < hi; i += 256) {
            eu4 v = __builtin_nontemporal_load(p4 + i);
            acc |= (v[0] << 1) | (v[1] << 1) | (v[2] << 1) | (v[3] << 1);
        }
        if (part == 3 && tid == 0) acc |= (p[NSEQ*NSEQ - 1] << 1);  // tail elem
        if (__any(acc != 0) && (tid & 63) == 0) atomicOr(&mflag[w], 1u);
        return;
    }

    // ---- LN1 + gather + QKV GEMM ----
    const int w  = b / 6;
    const int n0 = (b - w*6) * 64;
    const int g = tid >> 5, l = tid & 31;
    {
        const float lw0 = n1w[l], lw1 = n1w[l+32], lw2 = n1w[l+64];
        const float lb0 = n1b[l], lb1 = n1b[l+32], lb2 = n1b[l+64];
        for (int rr = 0; rr < 8; ++rr) {
            int row = g * 8 + rr;
            int n = n0 + row;
            if (n < NSEQ) {
                const float* xr = x + (size_t)tok_index(w, n) * CDIM;
                float x0 = __builtin_nontemporal_load(xr + l);
                float x1 = __builtin_nontemporal_load(xr + l + 32);
                float x2 = __builtin_nontemporal_load(xr + l + 64);
                float s = x0 + x1 + x2;
                #pragma unroll
                for (int m = 16; m; m >>= 1) s += __shfl_xor(s, m, 32);
                float mu = s * (1.0f/96.0f);
                float d0 = x0-mu, d1 = x1-mu, d2 = x2-mu;
                float vv = d0*d0 + d1*d1 + d2*d2;
                #pragma unroll
                for (int m = 16; m; m >>= 1) vv += __shfl_xor(vv, m, 32);
                float rstd = rsqrtf(vv * (1.0f/96.0f) + LN_EPS);
                sX[row*104 + l]    = __float2bfloat16(d0 * rstd * lw0 + lb0);
                sX[row*104 + l+32] = __float2bfloat16(d1 * rstd * lw1 + lb1);
                sX[row*104 + l+64] = __float2bfloat16(d2 * rstd * lw2 + lb2);
            } else {
                sX[row*104 + l]    = __float2bfloat16(0.f);
                sX[row*104 + l+32] = __float2bfloat16(0.f);
                sX[row*104 + l+64] = __float2bfloat16(0.f);
            }
        }
    }
    __syncthreads();

    const int wv = tid >> 6, lane = tid & 63;
    const int l15 = lane & 15, h = lane >> 4;
    const int trow = wv*16 + l15;
    const int n = n0 + trow;

    I4S8 bx[3];
    #pragma unroll
    for (int ks = 0; ks < 3; ++ks)
        bx[ks].i = *(const int4*)&sX[trow*104 + ks*32 + h*8];

    for (int nt = 0; nt < 18; ++nt) {
        f32x4 acc = {0.f,0.f,0.f,0.f};
        #pragma unroll
        for (int ks = 0; ks < 3; ++ks) {
            I4S8 af;
            af.i = *(const int4*)(qkvt + (size_t)(nt*16 + l15)*96 + ks*32 + h*8);
            acc = __builtin_amdgcn_mfma_f32_16x16x32_bf16(af.s, bx[ks].s, acc, 0, 0, 0);
        }
        if (n < NSEQ) {
            const int colbase = nt*16 + 4*h;          // [0,288)
            const int sel = colbase / 96;
            const int rem = colbase - sel*96;
            const int head = rem >> 5, d0 = rem & 31;
            float4 bb = *(const float4*)&qkvb[colbase];
            float v0 = acc[0] + bb.x, v1 = acc[1] + bb.y;
            float v2 = acc[2] + bb.z, v3 = acc[3] + bb.w;
            if (sel == 0) { v0 *= QK_SCALE; v1 *= QK_SCALE; v2 *= QK_SCALE; v3 *= QK_SCALE; }
            __hip_bfloat16* dst = (sel == 0 ? qb : (sel == 1 ? kb : vb));
            *(uint2*)&dst[(((size_t)w*3 + head)*NSEQ + n)*32 + d0] =
                make_uint2(pk2(v0, v1), pk2(v2, v3));
        }
    }
}

// ------- Kernel 2: windowed attention via MFMA (streaming, no-max) ----------
template<bool UM>
__device__ __forceinline__ void attn_qloop(
    const __hip_bfloat16* __restrict__ qb, const float* __restrict__ bg,
    const float* __restrict__ mask, __hip_bfloat16* __restrict__ aob,
    const __hip_bfloat16* sK, const __hip_bfloat16* sVT,
    size_t base, int w, int head, int wid, int l15, int h)
{
    for (int mt = wid; mt < 22; mt += 8) {
        const int m = mt*16 + l15;
        const int mc = (m < NSEQ) ? m : (NSEQ-1);

        I4S8 qf;
        qf.i = *(const int4*)(qb + base + (size_t)mc*32 + h*8);

        const float* mrow = mask + ((size_t)w*NSEQ + mc)*NSEQ;
        const float* brow = bg   + ((size_t)head*NSEQ + mc)*NSEQ;

        float lsum = 0.f;
        f32x4 acc0 = {0.f,0.f,0.f,0.f}, acc1 = {0.f,0.f,0.f,0.f};

        auto step = [&](int t, float4 mkA, float4 bsA, float4 mkB, float4 bsB) {
            float p[8];
            {
                I4S8 kf;
                kf.i = *(const int4*)&sK[(t*16 + l15)*32 + h*8];
                f32x4 st = __builtin_amdgcn_mfma_f32_16x16x32_bf16(
                    kf.s, qf.s, (f32x4){0.f,0.f,0.f,0.f}, 0, 0, 0);
                if constexpr (UM) {
                    p[0] = __expf(st[0] + mkA.x + bsA.x);
                    p[1] = __expf(st[1] + mkA.y + bsA.y);
                    p[2] = __expf(st[2] + mkA.z + bsA.z);
                    p[3] = __expf(st[3] + mkA.w + bsA.w);
                } else {
                    p[0] = __expf(st[0] + bsA.x);
                    p[1] = __expf(st[1] + bsA.y);
                    p[2] = __expf(st[2] + bsA.z);
                    p[3] = __expf(st[3] + bsA.w);
                }
                lsum += (p[0] + p[1]) + (p[2] + p[3]);
            }
            {
                I4S8 kf;
                kf.i = *(const int4*)&sK[((t+1)*16 + l15)*32 + h*8];
                f32x4 st = __builtin_amdgcn_mfma_f32_16x16x32_bf16(
                    kf.s, qf.s, (f32x4){0.f,0.f,0.f,0.f}, 0, 0, 0);
                if constexpr (UM) {
                    p[4] = __expf(st[0] + mkB.x + bsB.x);
                    p[5] = __expf(st[1] + mkB.y + bsB.y);
                    p[6] = __expf(st[2] + mkB.z + bsB.z);
                    p[7] = __expf(st[3] + mkB.w + bsB.w);
                } else {
                    p[4] = __expf(st[0] + bsB.x);
                    p[5] = __expf(st[1] + bsB.y);
                    p[6] = __expf(st[2] + bsB.z);
                    p[7] = __expf(st[3] + bsB.w);
                }
                lsum += (p[4] + p[5]) + (p[6] + p[7]);
            }
            I4S8 pf;
            pf.i = make_int4(pk2(p[0], p[1]), pk2(p[2], p[3]),
                             pk2(p[4], p[5]), pk2(p[6], p[7]));
            const int vcol = t*16 + 4*h;
            uint2 va0 = *(const uint2*)&sVT[(l15     )*372 + vcol];
            uint2 vb0 = *(const uint2*)&sVT[(l15     )*372 + vcol + 16];
            uint2 va1 = *(const uint2*)&sVT[(16 + l15)*372 + vcol];
            uint2 vb1 = *(const uint2*)&sVT[(16 + l15)*372 + vcol + 16];
            I4S8 vf0; vf0.i = make_int4(va0.x, va0.y, vb0.x, vb0.y);
            I4S8 vf1; vf1.i = make_int4(va1.x, va1.y, vb1.x, vb1.y);
            acc0 = __builtin_amdgcn_mfma_f32_16x16x32_bf16(vf0.s, pf.s, acc0, 0, 0, 0);
            acc1 = __builtin_amdgcn_mfma_f32_16x16x32_bf16(vf1.s, pf.s, acc1, 0, 0, 0);
        };

        const float4 z4 = {0.f,0.f,0.f,0.f};
        float4 mkA = UM ? *(const float4*)&mrow[4*h]      : z4;
        float4 bsA =      *(const float4*)&brow[4*h];
        float4 mkB = UM ? *(const float4*)&mrow[16 + 4*h] : z4;
        float4 bsB =      *(const float4*)&brow[16 + 4*h];

        #pragma unroll 1
        for (int c = 0; c < 9; ++c) {
            const int nb = (2*c + 2)*16 + 4*h;
            float4 nmkA = UM ? *(const float4*)&mrow[nb]      : z4;
            float4 nbsA =      *(const float4*)&brow[nb];
            float4 nmkB = UM ? *(const float4*)&mrow[nb + 16] : z4;
            float4 nbsB =      *(const float4*)&brow[nb + 16];
            step(2*c, mkA, bsA, mkB, bsB);
            mkA = nmkA; bsA = nbsA; mkB = nmkB; bsB = nbsB;
        }

        {
            float4 nmkA = UM ? *(const float4*)&mrow[320 + 4*h] : z4;
            float4 nbsA =      *(const float4*)&brow[320 + 4*h];
            float4 nmkB = z4, nbsB;
            {
                const int nb = 336 + 4*h;
                int i0 = nb,   c0 = (i0 < NSEQ) ? i0 : (NSEQ-1);
                int i1 = nb+1, c1 = (i1 < NSEQ) ? i1 : (NSEQ-1);
                int i2 = nb+2, c2 = (i2 < NSEQ) ? i2 : (NSEQ-1);
                int i3 = nb+3, c3 = (i3 < NSEQ) ? i3 : (NSEQ-1);
                if constexpr (UM) {
                    nmkB.x = mrow[c0]; nmkB.y = mrow[c1];
                    nmkB.z = mrow[c2]; nmkB.w = mrow[c3];
                }
                nbsB.x = brow[c0]; nbsB.y = brow[c1];
                nbsB.z = brow[c2]; nbsB.w = brow[c3];
            }
            step(18, mkA, bsA, mkB, bsB);
            mkA = nmkA; bsA = nbsA; mkB = nmkB; bsB = nbsB;
        }

        {
            float p[8];
            {
                I4S8 kf;
                kf.i = *(const int4*)&sK[(20*16 + l15)*32 + h*8];
                f32x4 st = __builtin_amdgcn_mfma_f32_16x16x32_bf16(
                    kf.s, qf.s, (f32x4){0.f,0.f,0.f,0.f}, 0, 0, 0);
                if constexpr (UM) {
                    p[0] = __expf(st[0] + mkA.x + bsA.x);
                    p[1] = __expf(st[1] + mkA.y + bsA.y);
                    p[2] = __expf(st[2] + mkA.z + bsA.z);
                    p[3] = __expf(st[3] + mkA.w + bsA.w);
                } else {
                    p[0] = __expf(st[0] + bsA.x);
                    p[1] = __expf(st[1] + bsA.y);
                    p[2] = __expf(st[2] + bsA.z);
                    p[3] = __expf(st[3] + bsA.w);
                }
                lsum += (p[0] + p[1]) + (p[2] + p[3]);
            }
            {
                I4S8 kf;
                kf.i = *(const int4*)&sK[(21*16 + l15)*32 + h*8];
                f32x4 st = __builtin_amdgcn_mfma_f32_16x16x32_bf16(
                    kf.s, qf.s, (f32x4){0.f,0.f,0.f,0.f}, 0, 0, 0);
                float sb[4];
                if constexpr (UM) {
                    sb[0] = mkB.x + bsB.x; sb[1] = mkB.y + bsB.y;
                    sb[2] = mkB.z + bsB.z; sb[3] = mkB.w + bsB.w;
                } else {
                    sb[0] = bsB.x; sb[1] = bsB.y; sb[2] = bsB.z; sb[3] = bsB.w;
                }
                const int nb = 336 + 4*h;
                #pragma unroll
                for (int r = 0; r < 4; ++r) {
                    const int nn = nb + r;
                    float e = 0.f;
                    if (nn < NSEQ) e = __expf(st[r] + sb[r]);
                    p[4+r] = e; lsum += e;
                }
            }
            I4S8 pf;
            pf.i = make_int4(pk2(p[0], p[1]), pk2(p[2], p[3]),
                             pk2(p[4], p[5]), pk2(p[6], p[7]));
            const int vcol = 320 + 4*h;                // cols 343.. are zeroed
            uint2 va0 = *(const uint2*)&sVT[(l15     )*372 + vcol];
            uint2 vb0 = *(const uint2*)&sVT[(l15     )*372 + vcol + 16];
            uint2 va1 = *(const uint2*)&sVT[(16 + l15)*372 + vcol];
            uint2 vb1 = *(const uint2*)&sVT[(16 + l15)*372 + vcol + 16];
            I4S8 vf0; vf0.i = make_int4(va0.x, va0.y, vb0.x, vb0.y);
            I4S8 vf1; vf1.i = make_int4(va1.x, va1.y, vb1.x, vb1.y);
            acc0 = __builtin_amdgcn_mfma_f32_16x16x32_bf16(vf0.s, pf.s, acc0, 0, 0, 0);
            acc1 = __builtin_amdgcn_mfma_f32_16x16x32_bf16(vf1.s, pf.s, acc1, 0, 0, 0);
        }

        lsum += __shfl_xor(lsum, 16, 64);
        lsum += __shfl_xor(lsum, 32, 64);
        const float inv = 1.0f / lsum;

        if (m < NSEQ) {
            __hip_bfloat16* orow = &aob[((size_t)w*NSEQ + m)*CDIM + head*32];
            *(uint2*)&orow[4*h] =
                make_uint2(pk2(acc0[0]*inv, acc0[1]*inv), pk2(acc0[2]*inv, acc0[3]*inv));
            *(uint2*)&orow[16 + 4*h] =
                make_uint2(pk2(acc1[0]*inv, acc1[1]*inv), pk2(acc1[2]*inv, acc1[3]*inv));
        }
    }
}

__global__ __launch_bounds__(512) void k_attn(
    const __hip_bfloat16* __restrict__ qb, const __hip_bfloat16* __restrict__ kb,
    const __hip_bfloat16* __restrict__ vb, const float* __restrict__ bg,
    const float* __restrict__ mask, const unsigned* __restrict__ mflag,
    __hip_bfloat16* __restrict__ aob)
{
    __shared__ __hip_bfloat16 sK[352*32];      // K rows [343][32], 64B stride
    __shared__ __hip_bfloat16 sVT[32*372];     // V^T [32][343], stride 372
    const int tid = threadIdx.x;
    const int v = blockIdx.x;
    const int xcd = v & 7, tt = v >> 3;
    const int j = tt / 3, head = tt - 3*j;
    const int w = xcd + 8*j;
    const size_t base = ((size_t)w*3 + head) * (NSEQ*32);

    {
        const int4* ksrc = (const int4*)(kb + base);
        for (int i = tid; i < NSEQ*4; i += 512) {
            int row = i >> 2, q = i & 3;
            *(int4*)&sK[row*32 + q*8] = ksrc[i];
        }
        const int4* vsrc = (const int4*)(vb + base);
        for (int i = tid; i < NSEQ*4; i += 512) {
            int n = i >> 2, dc = i & 3;
            int4 t = vsrc[i];
            const __hip_bfloat16* tp = (const __hip_bfloat16*)&t;
            #pragma unroll
            for (int k2 = 0; k2 < 8; ++k2) sVT[(dc*8 + k2)*372 + n] = tp[k2];
        }
        for (int i = tid; i < 32*29; i += 512) {   // zero cols 343..371
            int d = i / 29, n = NSEQ + (i - d*29);
            sVT[d*372 + n] = __float2bfloat16(0.f);
        }
    }
    __syncthreads();

    const int wid = tid >> 6, lane = tid & 63;
    const int l15 = lane & 15, h = lane >> 4;

    if (mflag[w] == 0)
        attn_qloop<false>(qb, bg, mask, aob, sK, sVT, base, w, head, wid, l15, h);
    else
        attn_qloop<true>(qb, bg, mask, aob, sK, sVT, base, w, head, wid, l15, h);
}

// ---- Kernel 3: fused proj+residual+LN2+FC1+GELU+FC2+residual ---------------
// Double-buffered weight staging: FC1 reads sW[1], proj/FC2 read sW[0].
// Each phase: issue next tile's global loads into 18 regs (T14 issue-early),
// compute from the OTHER buffer, then ds_write + one barrier -> stage latency
// hides under MFMA+gelu compute; 9 barriers total (was 18).
__global__ __launch_bounds__(256) void k_pmlp(
    const __hip_bfloat16* __restrict__ aob, const __hip_bfloat16* __restrict__ pwt,
    const float* __restrict__ pb, const float* __restrict__ x,
    const float* __restrict__ n2w, const float* __restrict__ n2b,
    const __hip_bfloat16* __restrict__ w1t, const float* __restrict__ b1,
    const __hip_bfloat16* __restrict__ w2t, const float* __restrict__ b2,
    float* __restrict__ out)
{
    __shared__ __align__(16) __hip_bfloat16 sBuf[64*104];   // sX / sMid-quarter
    __shared__ __align__(16) __hip_bfloat16 sW[2][96*100];  // ping-pong weight tiles
    const int w = blockIdx.y;
    const int n0 = blockIdx.x * 64;
    const int tid = threadIdx.x;
    const int wv = tid >> 6, lane = tid & 63;
    const int l15 = lane & 15, h = lane >> 4;
    const int trow = wv*16 + l15;
    const int n = n0 + trow;
    const int nc = (n < NSEQ) ? n : (NSEQ-1);
    const int tok = tok_index(w, nc);

    uint2 st[9];
    auto stage_load = [&](const __hip_bfloat16* src, int stride) {
        #pragma unroll
        for (int r = 0; r < 9; ++r) {
            int i = tid + r*256;
            int row = i / 24, cb = i - row*24;      // 24 uint2 per 96-col row
            st[r] = *(const uint2*)(src + (size_t)row*stride + cb*4);
        }
    };
    auto stage_write = [&](int buf) {
        #pragma unroll
        for (int r = 0; r < 9; ++r) {
            int i = tid + r*256;
            int row = i / 24, cb = i - row*24;
            *(uint2*)&sW[buf][row*100 + cb*4] = st[r];
        }
    };

    // ---- P0: stage pwt -> sW0 ----
    stage_load(pwt, 96);
    I4S8 bm[3];
    #pragma unroll
    for (int ks = 0; ks < 3; ++ks)
        bm[ks].i = *(const int4*)(aob + ((size_t)w*NSEQ + nc)*CDIM + ks*32 + h*8);
    stage_write(0);
    __syncthreads();

    // ---- P1: proj from sW0 + residual + LN2; stage w1q0 -> sW1 ----
    stage_load(w1t, 96);
    float4 x1v[6];
    #pragma unroll
    for (int nt = 0; nt < 6; ++nt) {
        f32x4 acc = {0.f,0.f,0.f,0.f};
        #pragma unroll
        for (int ks = 0; ks < 3; ++ks) {
            I4S8 af;
            af.i = *(const int4*)&sW[0][(nt*16 + l15)*100 + ks*32 + h*8];
            acc = __builtin_amdgcn_mfma_f32_16x16x32_bf16(af.s, bm[ks].s, acc, 0, 0, 0);
        }
        const int col = nt*16 + 4*h;
        float4 xr = *(const float4*)&x[(size_t)tok*CDIM + col];
        float4 bb = *(const float4*)&pb[col];
        x1v[nt].x = xr.x + acc[0] + bb.x;
        x1v[nt].y = xr.y + acc[1] + bb.y;
        x1v[nt].z = xr.z + acc[2] + bb.z;
        x1v[nt].w = xr.w + acc[3] + bb.w;
    }
    {
        float s = 0.f, q = 0.f;
        #pragma unroll
        for (int nt = 0; nt < 6; ++nt) {
            s += (x1v[nt].x + x1v[nt].y) + (x1v[nt].z + x1v[nt].w);
            q += (x1v[nt].x*x1v[nt].x + x1v[nt].y*x1v[nt].y)
               + (x1v[nt].z*x1v[nt].z + x1v[nt].w*x1v[nt].w);
        }
        s += __shfl_xor(s, 16, 64); s += __shfl_xor(s, 32, 64);
        q += __shfl_xor(q, 16, 64); q += __shfl_xor(q, 32, 64);
        float mu = s * (1.0f/96.0f);
        float var = q * (1.0f/96.0f) - mu*mu;
        float rstd = rsqrtf(var + LN_EPS);
        #pragma unroll
        for (int nt = 0; nt < 6; ++nt) {
            const int col = nt*16 + 4*h;
            float4 nwv = *(const float4*)&n2w[col];
            float4 nbv = *(const float4*)&n2b[col];
            float a0 = (x1v[nt].x - mu)*rstd*nwv.x + nbv.x;
            float a1 = (x1v[nt].y - mu)*rstd*nwv.y + nbv.y;
            float a2 = (x1v[nt].z - mu)*rstd*nwv.z + nbv.z;
            float a3 = (x1v[nt].w - mu)*rstd*nwv.w + nbv.w;
            *(uint2*)&sBuf[trow*104 + col] = make_uint2(pk2(a0, a1), pk2(a2, a3));
        }
    }
    I4S8 bx[3];
    #pragma unroll
    for (int ks = 0; ks < 3; ++ks)
        bx[ks].i = *(const int4*)&sBuf[trow*104 + ks*32 + h*8];
    stage_write(1);
    __syncthreads();

    f32x4 accs[6];
    #pragma unroll
    for (int nt = 0; nt < 6; ++nt) accs[nt] = (f32x4){0.f,0.f,0.f,0.f};

    // ---- 4 quarters: {FC1q(sW1), stage w2q->sW0} ; {FC2q(sW0), stage w1q+1->sW1}
    #pragma unroll 1
    for (int q = 0; q < 4; ++q) {
        stage_load(w2t + q*96, 384);
        #pragma unroll
        for (int ntl = 0; ntl < 6; ++ntl) {
            I4S8 af[3];
            #pragma unroll
            for (int ks = 0; ks < 3; ++ks)
                af[ks].i = *(const int4*)&sW[1][(ntl*16 + l15)*100 + ks*32 + h*8];
            f32x4 acc = {0.f,0.f,0.f,0.f};
            #pragma unroll
            for (int ks = 0; ks < 3; ++ks)
                acc = __builtin_amdgcn_mfma_f32_16x16x32_bf16(af[ks].s, bx[ks].s, acc, 0, 0, 0);
            float4 bb = *(const float4*)&b1[q*96 + ntl*16 + 4*h];
            *(uint2*)&sBuf[trow*104 + ntl*16 + 4*h] =
                make_uint2(pk2(gelu(acc[0]+bb.x), gelu(acc[1]+bb.y)),
                           pk2(gelu(acc[2]+bb.z), gelu(acc[3]+bb.w)));
        }
        stage_write(0);
        __syncthreads();

        if (q < 3) stage_load(w1t + (size_t)(q+1)*96*96, 96);
        #pragma unroll
        for (int ksl = 0; ksl < 3; ++ksl) {
            I4S8 bmq;
            bmq.i = *(const int4*)&sBuf[trow*104 + ksl*32 + h*8];
            #pragma unroll
            for (int nt = 0; nt < 6; ++nt) {
                I4S8 af;
                af.i = *(const int4*)&sW[0][(nt*16 + l15)*100 + ksl*32 + h*8];
                accs[nt] = __builtin_amdgcn_mfma_f32_16x16x32_bf16(af.s, bmq.s, accs[nt], 0, 0, 0);
            }
        }
        if (q < 3) {
            stage_write(1);
            __syncthreads();
        }
    }

    // ---- residual (x1v regs) + bias -> out ----
    if (n < NSEQ) {
        #pragma unroll
        for (int nt = 0; nt < 6; ++nt) {
            const int col = nt*16 + 4*h;
            float4 bb = *(const float4*)&b2[col];
            float4 o;
            o.x = x1v[nt].x + accs[nt][0] + bb.x;
            o.y = x1v[nt].y + accs[nt][1] + bb.y;
            o.z = x1v[nt].z + accs[nt][2] + bb.z;
            o.w = x1v[nt].w + accs[nt][3] + bb.w;
            *(float4*)&out[(size_t)tok*CDIM + col] = o;
        }
    }
}

extern "C" void kernel_launch(void* const* d_in, const int* in_sizes, int n_in,
                              void* d_out, int out_size, void* d_ws, size_t ws_size,
                              hipStream_t stream) {
    const float* x    = (const float*)d_in[0];
    const float* mask = (const float*)d_in[1];
    const float* n1w  = (const float*)d_in[2];
    const float* n1b  = (const float*)d_in[3];
    const float* qkvw = (const float*)d_in[4];
    const float* qkvb = (const float*)d_in[5];
    const float* pw   = (const float*)d_in[6];
    const float* pb   = (const float*)d_in[7];
    const float* rpb  = (const float*)d_in[8];
    const float* n2w  = (const float*)d_in[9];
    const float* n2b  = (const float*)d_in[10];
    const float* w1   = (const float*)d_in[11];
    const float* b1   = (const float*)d_in[12];
    const float* w2   = (const float*)d_in[13];
    const float* b2   = (const float*)d_in[14];
    float* out = (float*)d_out;

    __hip_bfloat16* qb  = (__hip_bfloat16*)d_ws;
    __hip_bfloat16* kb  = qb + NTOT;
    __hip_bfloat16* vb  = kb + NTOT;
    __hip_bfloat16* aob = vb + NTOT;                       // [216][343][96] bf16
    float* bg = (float*)(aob + NTOT);                      // [3][343][343] f32
    __hip_bfloat16* w1t  = (__hip_bfloat16*)(bg + 352948); // [384][96]
    __hip_bfloat16* w2t  = w1t + 384*96;                   // [96][384]
    __hip_bfloat16* pwt  = w2t + 96*384;                   // [96][96]
    __hip_bfloat16* qkvt = pwt + 96*96;                    // [288][96]
    unsigned* mflag = (unsigned*)(qkvt + 288*96);          // [216]

    hipLaunchKernelGGL(k_wcast, dim3(865), dim3(384), 0, stream,
                       w1, w2, pw, qkvw, w1t, w2t, pwt, qkvt, mflag);
    hipLaunchKernelGGL(k_fused_prep, dim3(1296 + 4*NWIN + NSEQ*3), dim3(256), 0, stream,
                       x, n1w, n1b, qkvt, qkvb, qb, kb, vb, mask, mflag, rpb, bg);
    hipLaunchKernelGGL(k_attn, dim3(NWIN*3), dim3(512), 0, stream,
                       qb, kb, vb, bg, mask, mflag, aob);
    hipLaunchKernelGGL(k_pmlp, dim3(6, NWIN), dim3(256), 0, stream,
                       aob, pwt, pb, x, n2w, n2b, w1t, b1, w2t, b2, out);
}